// Round 3
// baseline (379.566 us; speedup 1.0000x reference)
//
#include <hip/hip_runtime.h>
#include <math.h>

// PrimitiveTokenizer round 3:
//  prep:   all 4 weight matrices -> bf16 hi/lo MFMA B-fragment planes in ws.
//  window: per block = 512 slots = 8 rows. Compaction by kind (16-padded),
//          chunks of 16 slots: FF (hw sin/cos) -> GEMM1 (MFMA bf16x3) -> gelu
//          -> fp32 LDS atomicAdd pooling per (row,kind). Pool -> bf16 hi/lo
//          planes in ws + per-(row,kind) counts + denom.
//  fuse:   per block = 64 rows. GEMM2 batched over 8 kinds (pool @ w2,
//          accumulated in regs), + cnt*(b2+kind_emb), /denom -> h in LDS
//          (swizzled) -> fuse GEMM1 (K=768, embeddings gathered inline) ->
//          gelu -> fuse GEMM2 -> + meta linear -> out. h_num never hits HBM.

#define NWIN 512
#define WIN  512
#define RPW  8

// ws layout (short element offsets unless noted)
#define W2F_HI   0
#define W2F_LO   524288
#define W1F_HI   1048576
#define W1F_LO   1179648
#define FW1F_HI  1310720
#define FW1F_LO  1507328
#define FW2F_HI  1703936
#define FW2F_LO  1769472
#define POOL_HI  1835008
#define POOL_LO  10223616
#define CNT_BYTE 37224448ull
#define DEN_BYTE 37355520ull

typedef __attribute__((ext_vector_type(8))) short frag;
typedef __attribute__((ext_vector_type(4))) float f32x4;

__device__ __forceinline__ unsigned short f2bf_rn(float x) {
    unsigned int u = __float_as_uint(x);
    unsigned int r = (u + 0x7fffu + ((u >> 16) & 1u)) >> 16;
    return (unsigned short)r;
}
__device__ __forceinline__ float bf2f(unsigned short h) {
    return __uint_as_float(((unsigned int)h) << 16);
}
__device__ __forceinline__ void split_bf(float x, unsigned short& h, unsigned short& l) {
    unsigned short hh = f2bf_rn(x);
    h = hh;
    l = f2bf_rn(x - bf2f(hh));
}

// |abs err| <= ~1.5e-7 (Abramowitz-Stegun 7.1.26 erf), far under tolerance.
__device__ __forceinline__ float gelu_fast(float x) {
    float u = fabsf(x) * 0.7071067811865476f;
    float t = __builtin_amdgcn_rcpf(fmaf(0.3275911f, u, 1.0f));
    float p = fmaf(fmaf(fmaf(fmaf(1.061405429f, t, -1.453152027f), t,
                             1.421413741f), t, -0.284496736f), t, 0.254829592f) * t;
    float e = __expf(-u * u);
    float er = fmaf(-p, e, 1.0f);
    er = copysignf(er, x);
    return 0.5f * x * (1.0f + er);
}

// ---------------- prep: weights -> bf16 hi/lo fragment planes ----------------
__global__ __launch_bounds__(512) void prep_kernel(
    const float* __restrict__ w1, const float* __restrict__ w2,
    const float* __restrict__ fw1, const float* __restrict__ fw2,
    short* __restrict__ ws)
{
    int tid = blockIdx.x * 512 + threadIdx.x;
    int fid = tid >> 6, ln = tid & 63;
    if (fid >= 1792) return;
    int lr = ln & 15, kq = ln >> 4;
    float v[8];
    int dhi, dlo, dsto;
    if (fid < 1024) {                       // w2: [8k][8kst][16nt]
        int k = fid >> 7, kst = (fid >> 4) & 7, nt = fid & 15;
        int col = nt * 16 + lr;
        #pragma unroll
        for (int b = 0; b < 8; ++b) {
            int kg = kst * 32 + kq * 8 + b;
            v[b] = w2[(k * 256 + kg) * 256 + col];
        }
        dsto = fid * 512 + ln * 8; dhi = W2F_HI; dlo = W2F_LO;
    } else if (fid < 1280) {                // w1: [8k][2kst][16nt], K padded 48->64
        int f = fid - 1024;
        int k = f >> 5, kst = (f >> 4) & 1, nt = f & 15;
        int col = nt * 16 + lr;
        #pragma unroll
        for (int b = 0; b < 8; ++b) {
            int kg = kst * 32 + kq * 8 + b;
            v[b] = (kg < 48) ? w1[(k * 48 + kg) * 256 + col] : 0.0f;
        }
        dsto = f * 512 + ln * 8; dhi = W1F_HI; dlo = W1F_LO;
    } else if (fid < 1664) {                // fw1: [24kst][16nt]
        int f = fid - 1280;
        int kst = f >> 4, nt = f & 15;
        int col = nt * 16 + lr;
        #pragma unroll
        for (int b = 0; b < 8; ++b) {
            int kg = kst * 32 + kq * 8 + b;
            v[b] = fw1[kg * 256 + col];
        }
        dsto = f * 512 + ln * 8; dhi = FW1F_HI; dlo = FW1F_LO;
    } else {                                // fw2: [8kst][16nt]
        int f = fid - 1664;
        int kst = f >> 4, nt = f & 15;
        int col = nt * 16 + lr;
        #pragma unroll
        for (int b = 0; b < 8; ++b) {
            int kg = kst * 32 + kq * 8 + b;
            v[b] = fw2[kg * 256 + col];
        }
        dsto = f * 512 + ln * 8; dhi = FW2F_HI; dlo = FW2F_LO;
    }
    union { unsigned short u[8]; frag f; } hu, lu;
    #pragma unroll
    for (int b = 0; b < 8; ++b) split_bf(v[b], hu.u[b], lu.u[b]);
    *(frag*)(ws + dhi + dsto) = hu.f;
    *(frag*)(ws + dlo + dsto) = lu.f;
}

// ---------------- window kernel ----------------
__global__ __launch_bounds__(512, 4) void window_kernel(
    const float* __restrict__ values, const int* __restrict__ kinds,
    const int* __restrict__ mask, const float* __restrict__ B_ff,
    const float* __restrict__ b1, short* __restrict__ ws,
    float* __restrict__ cntf, float* __restrict__ denf)
{
    __shared__ float vals[WIN];
    __shared__ unsigned char knd[WIN], msk[WIN];
    __shared__ unsigned short list[WIN + 128];
    __shared__ int off_s[8], nch_s[8];
    __shared__ float Bs[24];
    __shared__ float pool_s[RPW * 257];
    __shared__ short ffh[2][1024], ffl[2][1024];   // [buf][16 rows][64 cols] swizzled

    const short* w1f_hi = ws + W1F_HI;
    const short* w1f_lo = ws + W1F_LO;
    short* poolhi = ws + POOL_HI;
    short* poollo = ws + POOL_LO;

    const int t = threadIdx.x, w = blockIdx.x, base = w * WIN;
    const int wv = t >> 6, ln = t & 63, lr = ln & 15, kq = ln >> 4;
    const int col0 = wv * 32 + lr, col1 = col0 + 16;

    for (int i = t; i < WIN; i += 512) {
        vals[i] = values[base + i];
        knd[i]  = (unsigned char)kinds[base + i];
        msk[i]  = (unsigned char)mask[base + i];
    }
    if (t < 24) Bs[t] = B_ff[t];
    for (int i = t; i < RPW * 257; i += 512) pool_s[i] = 0.0f;
    // zero ff K-pad chunks 6,7 (swizzled positions), both bufs/planes, once
    for (int i = t; i < 1024; i += 512) {
        int j = i & 7, q = 6 + ((i >> 3) & 1), s = (i >> 4) & 15;
        int pb = (i >> 8) & 1, bb = (i >> 9) & 1;
        int pos = s * 64 + ((q ^ (s & 7)) << 3) + j;
        if (pb) ffl[bb][pos] = 0; else ffh[bb][pos] = 0;
    }
    __syncthreads();

    if (t < 64) {
        // deterministic per-kind compaction, padded to multiples of 16
        int cnts[8];
        #pragma unroll
        for (int k = 0; k < 8; ++k) cnts[k] = 0;
        for (int c = 0; c < WIN / 64; ++c) {
            int p = c * 64 + t;
            int kd = knd[p], mk = msk[p];
            #pragma unroll
            for (int k = 0; k < 8; ++k) {
                unsigned long long bal = __ballot(mk && (kd == k));
                cnts[k] += __popcll(bal);
            }
        }
        int offk[8], run = 0;
        #pragma unroll
        for (int k = 0; k < 8; ++k) { offk[k] = run; run += (cnts[k] + 15) & ~15; }
        if (t == 0) {
            #pragma unroll
            for (int k = 0; k < 8; ++k) { off_s[k] = offk[k]; nch_s[k] = (cnts[k] + 15) >> 4; }
        }
        int fillk[8];
        #pragma unroll
        for (int k = 0; k < 8; ++k) fillk[k] = 0;
        const unsigned long long below = (1ull << t) - 1ull;
        for (int c = 0; c < WIN / 64; ++c) {
            int p = c * 64 + t;
            int kd = knd[p], mk = msk[p];
            #pragma unroll
            for (int k = 0; k < 8; ++k) {
                unsigned long long bal = __ballot(mk && (kd == k));
                if (mk && (kd == k)) {
                    int rank = __popcll(bal & below);
                    list[offk[k] + fillk[k] + rank] = (unsigned short)p;
                }
                fillk[k] += __popcll(bal);
            }
        }
        #pragma unroll
        for (int k = 0; k < 8; ++k) {
            int padded = (cnts[k] + 15) & ~15;
            for (int i = cnts[k] + t; i < padded; i += 64) list[offk[k] + i] = 0xFFFFu;
        }
    } else if (t < 128) {
        int i = t - 64, r = i >> 3, k = i & 7, c = 0;
        for (int s = 0; s < 64; ++s) c += (msk[r * 64 + s] && knd[r * 64 + s] == k) ? 1 : 0;
        cntf[(w * RPW + r) * 8 + k] = (float)c;
    } else if (t < 136) {
        int r = t - 128, c = 0;
        for (int s = 0; s < 64; ++s) c += msk[r * 64 + s];
        denf[w * RPW + r] = 1.0f / (float)(c > 0 ? c : 1);
    }
    __syncthreads();

    auto ff_phase = [&](int off, int c, int b) {
        if (t < 384) {
            int s = t / 24, j = t - s * 24;
            int e = list[off + c * 16 + s];
            float v = vals[e & (WIN - 1)];
            float rev = v * Bs[j];
            rev -= floorf(rev);                 // exact range reduction to [0,1)
            float ang = rev * 6.2831853071795865f;
            float sn = __sinf(ang), cs = __cosf(ang);
            unsigned short sh, sl, ch2, cl2;
            split_bf(sn, sh, sl); split_bf(cs, ch2, cl2);
            int q1 = j >> 3, q2 = (j + 24) >> 3;
            int p1 = s * 64 + ((q1 ^ (s & 7)) << 3) + (j & 7);
            int p2 = s * 64 + ((q2 ^ (s & 7)) << 3) + ((j + 24) & 7);
            ffh[b][p1] = (short)sh; ffl[b][p1] = (short)sl;
            ffh[b][p2] = (short)ch2; ffl[b][p2] = (short)cl2;
        }
    };

    for (int k8 = 0; k8 < 8; ++k8) {
        const int nch = nch_s[k8], off = off_s[k8];
        const float b1v0 = b1[k8 * 256 + col0], b1v1 = b1[k8 * 256 + col1];
        if (nch > 0) ff_phase(off, 0, 0);
        __syncthreads();
        for (int c = 0; c < nch; ++c) {
            const int p = c & 1;
            frag ah[2], al[2];
            #pragma unroll
            for (int kst = 0; kst < 2; ++kst) {
                int cq = kst * 4 + kq;
                int a = lr * 64 + ((cq ^ (lr & 7)) << 3);
                ah[kst] = *(const frag*)&ffh[p][a];
                al[kst] = *(const frag*)&ffl[p][a];
            }
            if (c + 1 < nch) ff_phase(off, c + 1, p ^ 1);
            f32x4 a0 = (f32x4)0.0f, a1 = (f32x4)0.0f;
            #pragma unroll
            for (int kst = 0; kst < 2; ++kst) {
                int fb = ((k8 * 2 + kst) * 16 + wv * 2) * 512 + ln * 8;
                frag bh0 = *(const frag*)(w1f_hi + fb), bl0 = *(const frag*)(w1f_lo + fb);
                frag bh1 = *(const frag*)(w1f_hi + fb + 512), bl1 = *(const frag*)(w1f_lo + fb + 512);
                a0 = __builtin_amdgcn_mfma_f32_16x16x32_bf16(ah[kst], bh0, a0, 0, 0, 0);
                a0 = __builtin_amdgcn_mfma_f32_16x16x32_bf16(al[kst], bh0, a0, 0, 0, 0);
                a0 = __builtin_amdgcn_mfma_f32_16x16x32_bf16(ah[kst], bl0, a0, 0, 0, 0);
                a1 = __builtin_amdgcn_mfma_f32_16x16x32_bf16(ah[kst], bh1, a1, 0, 0, 0);
                a1 = __builtin_amdgcn_mfma_f32_16x16x32_bf16(al[kst], bh1, a1, 0, 0, 0);
                a1 = __builtin_amdgcn_mfma_f32_16x16x32_bf16(ah[kst], bl1, a1, 0, 0, 0);
            }
            #pragma unroll
            for (int r = 0; r < 4; ++r) {
                int e = list[off + c * 16 + kq * 4 + r];
                float g0 = gelu_fast(a0[r] + b1v0);
                float g1 = gelu_fast(a1[r] + b1v1);
                if (e != 0xFFFF) {
                    int row = (e >> 6) & 7;
                    atomicAdd(&pool_s[row * 257 + col0], g0);
                    atomicAdd(&pool_s[row * 257 + col1], g1);
                }
            }
            __syncthreads();
        }
        // pool write-out (bf16 hi/lo planes) + rezero
        for (int i = t; i < RPW * 256; i += 512) {
            int r = i >> 8, cc = i & 255;
            float v = pool_s[r * 257 + cc];
            pool_s[r * 257 + cc] = 0.0f;
            unsigned short h, l; split_bf(v, h, l);
            size_t gi = ((size_t)((w * 8 + k8) * 8 + r)) * 256 + cc;
            poolhi[gi] = (short)h; poollo[gi] = (short)l;
        }
    }
}

// ---------------- fused GEMM2 + fuse MLP kernel ----------------
__global__ __launch_bounds__(1024, 4) void fuse_kernel(
    const short* __restrict__ ws, const float* __restrict__ cntf,
    const float* __restrict__ denf, const int* __restrict__ pt,
    const int* __restrict__ lid, const float* __restrict__ meta,
    const float* __restrict__ type_emb, const float* __restrict__ layer_emb,
    const float* __restrict__ b2, const float* __restrict__ kind_emb,
    const float* __restrict__ fb1, const float* __restrict__ fb2,
    const float* __restrict__ meta_w, const float* __restrict__ meta_b,
    float* __restrict__ out)
{
    __shared__ short Abuf[2][32768];      // 128 KB; Abuf[0] later = h/z fp32 [64][256]
    __shared__ float cnt_s[512];
    __shared__ int pt_s[64], lid_s[64];
    __shared__ float den_s[64], meta_s[256];

    const short* w2f_hi  = ws + W2F_HI;
    const short* w2f_lo  = ws + W2F_LO;
    const short* fw1f_hi = ws + FW1F_HI;
    const short* fw1f_lo = ws + FW1F_LO;
    const short* fw2f_hi = ws + FW2F_HI;
    const short* fw2f_lo = ws + FW2F_LO;
    const short* poolhi  = ws + POOL_HI;
    const short* poollo  = ws + POOL_LO;

    const int t = threadIdx.x, blk = blockIdx.x, rb = blk * 64;
    const int wv = t >> 6, ln = t & 63, lr = ln & 15, kq = ln >> 4;
    const int col = wv * 16 + lr;          // nt = wv

    if (t < 64) { pt_s[t] = pt[rb + t]; lid_s[t] = lid[rb + t]; den_s[t] = denf[rb + t]; }
    else if (t < 576) cnt_s[t - 64] = cntf[rb * 8 + (t - 64)];
    else if (t < 832) meta_s[t - 576] = meta[rb * 4 + (t - 576)];

    uint4 stg[4];
    auto stage_load = [&](int k) {
        #pragma unroll
        for (int i = 0; i < 4; ++i) {
            int ch = wv * 4 + i;
            int pl = ch >> 5, mt = (ch >> 3) & 3, kst = ch & 7;
            int win = blk * 8 + 2 * mt + (lr >> 3), r8 = lr & 7;
            const short* s = (pl ? poollo : poolhi)
                           + (((size_t)win * 8 + k) * 8 + r8) * 256 + kst * 32 + kq * 8;
            stg[i] = *(const uint4*)s;
        }
    };
    auto stage_write = [&](int buf) {
        #pragma unroll
        for (int i = 0; i < 4; ++i) {
            int ch = wv * 4 + i;
            *(uint4*)&Abuf[buf][ch * 512 + ln * 8] = stg[i];
        }
    };
    stage_load(0); stage_write(0);
    __syncthreads();

    // phase A: h_pre = sum_k pool[k] @ w2[k]
    f32x4 acc[4];
    #pragma unroll
    for (int mt = 0; mt < 4; ++mt) acc[mt] = (f32x4)0.0f;

    for (int k8 = 0; k8 < 8; ++k8) {
        const int p = k8 & 1;
        if (k8 < 7) stage_load(k8 + 1);
        #pragma unroll 2
        for (int kst = 0; kst < 8; ++kst) {
            frag ah[4], al[4];
            #pragma unroll
            for (int mt = 0; mt < 4; ++mt) {
                ah[mt] = *(const frag*)&Abuf[p][(mt * 8 + kst) * 512 + ln * 8];
                al[mt] = *(const frag*)&Abuf[p][16384 + (mt * 8 + kst) * 512 + ln * 8];
            }
            size_t bo = (((size_t)k8 * 8 + kst) * 16 + wv) * 512 + ln * 8;
            frag bh = *(const frag*)(w2f_hi + bo), bl = *(const frag*)(w2f_lo + bo);
            #pragma unroll
            for (int mt = 0; mt < 4; ++mt) {
                acc[mt] = __builtin_amdgcn_mfma_f32_16x16x32_bf16(ah[mt], bh, acc[mt], 0, 0, 0);
                acc[mt] = __builtin_amdgcn_mfma_f32_16x16x32_bf16(al[mt], bh, acc[mt], 0, 0, 0);
                acc[mt] = __builtin_amdgcn_mfma_f32_16x16x32_bf16(ah[mt], bl, acc[mt], 0, 0, 0);
            }
        }
        if (k8 < 7) stage_write(p ^ 1);
        __syncthreads();
    }

    // epilogue A: + cnt*(b2+kind_emb), * denom_inv -> h into LDS (16B-chunk XOR swizzle)
    float* hz = (float*)&Abuf[0][0];
    {
        float bk[8];
        #pragma unroll
        for (int k = 0; k < 8; ++k) bk[k] = b2[k * 256 + col] + kind_emb[k * 256 + col];
        #pragma unroll
        for (int mt = 0; mt < 4; ++mt) {
            #pragma unroll
            for (int r = 0; r < 4; ++r) {
                int row = mt * 16 + kq * 4 + r;
                float hv = acc[mt][r];
                #pragma unroll
                for (int k = 0; k < 8; ++k) hv = fmaf(cnt_s[row * 8 + k], bk[k], hv);
                hv *= den_s[row];
                int addr = row * 256 + (((col >> 2) ^ (row & 7)) << 2) + (col & 3);
                hz[addr] = hv;
            }
        }
    }
    __syncthreads();

    // phase B: z_pre = [h | type_emb | layer_emb] @ fw1   (K=768)
    f32x4 az[4];
    #pragma unroll
    for (int mt = 0; mt < 4; ++mt) az[mt] = (f32x4)0.0f;

    for (int kst = 0; kst < 24; ++kst) {
        frag ah[4], al[4];
        int seg = kst >> 3;
        if (seg == 0) {
            #pragma unroll
            for (int mt = 0; mt < 4; ++mt) {
                int row = mt * 16 + lr;
                int c0 = kst * 8 + kq * 2;
                f32x4 u0 = *(const f32x4*)&hz[row * 256 + ((c0 ^ (row & 7)) << 2)];
                f32x4 u1 = *(const f32x4*)&hz[row * 256 + (((c0 + 1) ^ (row & 7)) << 2)];
                union { unsigned short u[8]; frag f; } hu, lu;
                #pragma unroll
                for (int b = 0; b < 4; ++b) {
                    split_bf(u0[b], hu.u[b], lu.u[b]);
                    split_bf(u1[b], hu.u[b + 4], lu.u[b + 4]);
                }
                ah[mt] = hu.f; al[mt] = lu.f;
            }
        } else {
            const float* eb = (seg == 1) ? type_emb : layer_emb;
            const int* ids = (seg == 1) ? pt_s : lid_s;
            int ko = (kst - seg * 8) * 32 + kq * 8;
            #pragma unroll
            for (int mt = 0; mt < 4; ++mt) {
                int row = mt * 16 + lr;
                const float* sp = eb + (size_t)ids[row] * 256 + ko;
                f32x4 u0 = *(const f32x4*)sp;
                f32x4 u1 = *(const f32x4*)(sp + 4);
                union { unsigned short u[8]; frag f; } hu, lu;
                #pragma unroll
                for (int b = 0; b < 4; ++b) {
                    split_bf(u0[b], hu.u[b], lu.u[b]);
                    split_bf(u1[b], hu.u[b + 4], lu.u[b + 4]);
                }
                ah[mt] = hu.f; al[mt] = lu.f;
            }
        }
        size_t bo = ((size_t)kst * 16 + wv) * 512 + ln * 8;
        frag bh = *(const frag*)(fw1f_hi + bo), bl = *(const frag*)(fw1f_lo + bo);
        #pragma unroll
        for (int mt = 0; mt < 4; ++mt) {
            az[mt] = __builtin_amdgcn_mfma_f32_16x16x32_bf16(ah[mt], bh, az[mt], 0, 0, 0);
            az[mt] = __builtin_amdgcn_mfma_f32_16x16x32_bf16(al[mt], bh, az[mt], 0, 0, 0);
            az[mt] = __builtin_amdgcn_mfma_f32_16x16x32_bf16(ah[mt], bl, az[mt], 0, 0, 0);
        }
    }
    __syncthreads();     // all h reads done before z overwrites

    {
        float fb1v = fb1[col];
        #pragma unroll
        for (int mt = 0; mt < 4; ++mt) {
            #pragma unroll
            for (int r = 0; r < 4; ++r) {
                int row = mt * 16 + kq * 4 + r;
                float z = gelu_fast(az[mt][r] + fb1v);
                hz[row * 256 + (((col >> 2) ^ (row & 7)) << 2) + (col & 3)] = z;
            }
        }
    }
    __syncthreads();

    // phase C: out = z @ fw2 + fb2 + meta @ meta_w + meta_b
    f32x4 ao[4];
    #pragma unroll
    for (int mt = 0; mt < 4; ++mt) ao[mt] = (f32x4)0.0f;

    for (int kst = 0; kst < 8; ++kst) {
        frag ah[4], al[4];
        #pragma unroll
        for (int mt = 0; mt < 4; ++mt) {
            int row = mt * 16 + lr;
            int c0 = kst * 8 + kq * 2;
            f32x4 u0 = *(const f32x4*)&hz[row * 256 + ((c0 ^ (row & 7)) << 2)];
            f32x4 u1 = *(const f32x4*)&hz[row * 256 + (((c0 + 1) ^ (row & 7)) << 2)];
            union { unsigned short u[8]; frag f; } hu, lu;
            #pragma unroll
            for (int b = 0; b < 4; ++b) {
                split_bf(u0[b], hu.u[b], lu.u[b]);
                split_bf(u1[b], hu.u[b + 4], lu.u[b + 4]);
            }
            ah[mt] = hu.f; al[mt] = lu.f;
        }
        size_t bo = ((size_t)kst * 16 + wv) * 512 + ln * 8;
        frag bh = *(const frag*)(fw2f_hi + bo), bl = *(const frag*)(fw2f_lo + bo);
        #pragma unroll
        for (int mt = 0; mt < 4; ++mt) {
            ao[mt] = __builtin_amdgcn_mfma_f32_16x16x32_bf16(ah[mt], bh, ao[mt], 0, 0, 0);
            ao[mt] = __builtin_amdgcn_mfma_f32_16x16x32_bf16(al[mt], bh, ao[mt], 0, 0, 0);
            ao[mt] = __builtin_amdgcn_mfma_f32_16x16x32_bf16(ah[mt], bl, ao[mt], 0, 0, 0);
        }
    }

    {
        float ob = fb2[col] + meta_b[col];
        float mw0 = meta_w[col], mw1 = meta_w[256 + col];
        float mw2 = meta_w[512 + col], mw3 = meta_w[768 + col];
        #pragma unroll
        for (int mt = 0; mt < 4; ++mt) {
            #pragma unroll
            for (int r = 0; r < 4; ++r) {
                int row = mt * 16 + kq * 4 + r;
                float o = ao[mt][r] + ob;
                o = fmaf(meta_s[row * 4 + 0], mw0, o);
                o = fmaf(meta_s[row * 4 + 1], mw1, o);
                o = fmaf(meta_s[row * 4 + 2], mw2, o);
                o = fmaf(meta_s[row * 4 + 3], mw3, o);
                out[(size_t)(rb + row) * 256 + col] = o;
            }
        }
    }
}

extern "C" void kernel_launch(void* const* d_in, const int* in_sizes, int n_in,
                              void* d_out, int out_size, void* d_ws, size_t ws_size,
                              hipStream_t stream) {
    const float* values    = (const float*)d_in[0];
    const int*   kinds     = (const int*)d_in[1];
    const int*   mask      = (const int*)d_in[2];
    const int*   prim_type = (const int*)d_in[3];
    const int*   layer_id  = (const int*)d_in[4];
    const float* meta      = (const float*)d_in[5];
    const float* B_ff      = (const float*)d_in[6];
    const float* kind_emb  = (const float*)d_in[7];
    const float* type_emb  = (const float*)d_in[8];
    const float* layer_emb = (const float*)d_in[9];
    const float* mlp_w1    = (const float*)d_in[10];
    const float* mlp_b1    = (const float*)d_in[11];
    const float* mlp_w2    = (const float*)d_in[12];
    const float* mlp_b2    = (const float*)d_in[13];
    const float* fuse_w1   = (const float*)d_in[14];
    const float* fuse_b1   = (const float*)d_in[15];
    const float* fuse_w2   = (const float*)d_in[16];
    const float* fuse_b2   = (const float*)d_in[17];
    const float* meta_w    = (const float*)d_in[18];
    const float* meta_b    = (const float*)d_in[19];

    short* ws   = (short*)d_ws;
    float* cntf = (float*)((char*)d_ws + CNT_BYTE);
    float* denf = (float*)((char*)d_ws + DEN_BYTE);
    float* out  = (float*)d_out;

    prep_kernel<<<224, 512, 0, stream>>>(mlp_w1, mlp_w2, fuse_w1, fuse_w2, ws);
    window_kernel<<<NWIN, 512, 0, stream>>>(values, kinds, mask, B_ff, mlp_b1,
                                            ws, cntf, denf);
    fuse_kernel<<<64, 1024, 0, stream>>>(ws, cntf, denf, prim_type, layer_id, meta,
                                         type_emb, layer_emb, mlp_b2, kind_emb,
                                         fuse_b1, fuse_b2, meta_w, meta_b, out);
}

// Round 4
// 268.724 us; speedup vs baseline: 1.4125x; 1.4125x over previous
//
#include <hip/hip_runtime.h>
#include <math.h>

// PrimitiveTokenizer round 4:
//  prep:   4 weight matrices -> bf16 hi/lo MFMA B-fragment planes in ws (as R3).
//  window: 1024 blocks x 512 thr, 256 slots (4 rows) each. Per-kind compaction
//          (16-padded). Main loop is BARRIER-FREE: each wave owns 16-slot
//          chunks (wave-private LDS A staging, ds_add_f32 pooling).
//          Pool written to ws as fp32 [kind][row][col].
//  fuse:   256 blocks x 512 thr, 16 rows each. Phase A: h = sum_k pool@w2[k]
//          (double-buffered coalesced staging + split), + cnt*(b2+ke), /den.
//          Phase B: [h|type_emb|layer_emb]@fw1 (K=768), gelu. Phase C: @fw2,
//          + meta linear -> out.

#define WIN   256
#define ROWS  4
#define NWIN  1024

// ws layout (short offsets for frags; byte offsets for pool/cnt/den)
#define W2F_HI   0
#define W2F_LO   524288
#define W1F_HI   1048576
#define W1F_LO   1179648
#define FW1F_HI  1310720
#define FW1F_LO  1507328
#define FW2F_HI  1703936
#define FW2F_LO  1769472
#define POOL_BYTE 3670016ull
#define CNT_BYTE  37224448ull
#define DEN_BYTE  37355520ull

typedef __attribute__((ext_vector_type(8))) short frag;
typedef __attribute__((ext_vector_type(4))) float f32x4;

__device__ __forceinline__ unsigned short f2bf_rn(float x) {
    unsigned int u = __float_as_uint(x);
    unsigned int r = (u + 0x7fffu + ((u >> 16) & 1u)) >> 16;
    return (unsigned short)r;
}
__device__ __forceinline__ float bf2f(unsigned short h) {
    return __uint_as_float(((unsigned int)h) << 16);
}
__device__ __forceinline__ void split_bf(float x, unsigned short& h, unsigned short& l) {
    unsigned short hh = f2bf_rn(x);
    h = hh;
    l = f2bf_rn(x - bf2f(hh));
}

// |abs err| <= ~1.5e-7 (A&S 7.1.26 erf)
__device__ __forceinline__ float gelu_fast(float x) {
    float u = fabsf(x) * 0.7071067811865476f;
    float t = __builtin_amdgcn_rcpf(fmaf(0.3275911f, u, 1.0f));
    float p = fmaf(fmaf(fmaf(fmaf(1.061405429f, t, -1.453152027f), t,
                             1.421413741f), t, -0.284496736f), t, 0.254829592f) * t;
    float e = __expf(-u * u);
    float er = fmaf(-p, e, 1.0f);
    er = copysignf(er, x);
    return 0.5f * x * (1.0f + er);
}

// ---------------- prep: weights -> bf16 hi/lo fragment planes ----------------
__global__ __launch_bounds__(512) void prep_kernel(
    const float* __restrict__ w1, const float* __restrict__ w2,
    const float* __restrict__ fw1, const float* __restrict__ fw2,
    short* __restrict__ ws)
{
    int tid = blockIdx.x * 512 + threadIdx.x;
    int fid = tid >> 6, ln = tid & 63;
    if (fid >= 1792) return;
    int lr = ln & 15, kq = ln >> 4;
    float v[8];
    int dhi, dlo, dsto;
    if (fid < 1024) {                       // w2: [8k][8kst][16nt]
        int k = fid >> 7, kst = (fid >> 4) & 7, nt = fid & 15;
        int col = nt * 16 + lr;
        #pragma unroll
        for (int b = 0; b < 8; ++b) {
            int kg = kst * 32 + kq * 8 + b;
            v[b] = w2[(k * 256 + kg) * 256 + col];
        }
        dsto = fid * 512 + ln * 8; dhi = W2F_HI; dlo = W2F_LO;
    } else if (fid < 1280) {                // w1: [8k][2kst][16nt], K pad 48->64
        int f = fid - 1024;
        int k = f >> 5, kst = (f >> 4) & 1, nt = f & 15;
        int col = nt * 16 + lr;
        #pragma unroll
        for (int b = 0; b < 8; ++b) {
            int kg = kst * 32 + kq * 8 + b;
            v[b] = (kg < 48) ? w1[(k * 48 + kg) * 256 + col] : 0.0f;
        }
        dsto = f * 512 + ln * 8; dhi = W1F_HI; dlo = W1F_LO;
    } else if (fid < 1664) {                // fw1: [24kst][16nt]
        int f = fid - 1280;
        int kst = f >> 4, nt = f & 15;
        int col = nt * 16 + lr;
        #pragma unroll
        for (int b = 0; b < 8; ++b) {
            int kg = kst * 32 + kq * 8 + b;
            v[b] = fw1[kg * 256 + col];
        }
        dsto = f * 512 + ln * 8; dhi = FW1F_HI; dlo = FW1F_LO;
    } else {                                // fw2: [8kst][16nt]
        int f = fid - 1664;
        int kst = f >> 4, nt = f & 15;
        int col = nt * 16 + lr;
        #pragma unroll
        for (int b = 0; b < 8; ++b) {
            int kg = kst * 32 + kq * 8 + b;
            v[b] = fw2[kg * 256 + col];
        }
        dsto = f * 512 + ln * 8; dhi = FW2F_HI; dlo = FW2F_LO;
    }
    union { unsigned short u[8]; frag f; } hu, lu;
    #pragma unroll
    for (int b = 0; b < 8; ++b) split_bf(v[b], hu.u[b], lu.u[b]);
    *(frag*)(ws + dhi + dsto) = hu.f;
    *(frag*)(ws + dlo + dsto) = lu.f;
}

// ---------------- window kernel ----------------
__global__ __launch_bounds__(512, 4) void window_kernel(
    const float* __restrict__ values, const int* __restrict__ kinds,
    const int* __restrict__ mask, const float* __restrict__ B_ff,
    const float* __restrict__ b1, const short* __restrict__ wsf,
    float* __restrict__ poolf, float* __restrict__ cntf,
    float* __restrict__ denf)
{
    __shared__ float vals[WIN];
    __shared__ unsigned char knd[WIN], msk[WIN];
    __shared__ unsigned short list[WIN + 128];
    __shared__ short chunk_kind[32];
    __shared__ short chunk_base[32];
    __shared__ int nchT_s;
    __shared__ float Bs[24];
    __shared__ float pool_s[32 * 257];                 // [row*8+kind][257] 32.9 KB
    __shared__ __align__(16) short Asl[8][2][1024];    // [wave][plane][slot*64+col] 32 KB

    const short* w1f_hi = wsf + W1F_HI;
    const short* w1f_lo = wsf + W1F_LO;

    const int t = threadIdx.x, w = blockIdx.x, base = w * WIN;
    const int wv = t >> 6, ln = t & 63, lr16 = ln & 15, kq = ln >> 4;

    for (int i = t; i < WIN; i += 512) {
        vals[i] = values[base + i];
        knd[i]  = (unsigned char)kinds[base + i];
        msk[i]  = (unsigned char)mask[base + i];
    }
    if (t < 24) Bs[t] = B_ff[t];
    __syncthreads();

    if (t < 64) {
        // deterministic per-kind compaction, padded to multiples of 16
        int cnts[8];
        #pragma unroll
        for (int k = 0; k < 8; ++k) cnts[k] = 0;
        for (int c = 0; c < WIN / 64; ++c) {
            int p = c * 64 + t;
            int kd = knd[p], mk = msk[p];
            #pragma unroll
            for (int k = 0; k < 8; ++k) {
                unsigned long long bal = __ballot(mk && (kd == k));
                cnts[k] += __popcll(bal);
            }
        }
        int offk[8], run = 0;
        #pragma unroll
        for (int k = 0; k < 8; ++k) { offk[k] = run; run += (cnts[k] + 15) & ~15; }
        int fillk[8];
        #pragma unroll
        for (int k = 0; k < 8; ++k) fillk[k] = 0;
        const unsigned long long below = (1ull << t) - 1ull;
        for (int c = 0; c < WIN / 64; ++c) {
            int p = c * 64 + t;
            int kd = knd[p], mk = msk[p];
            #pragma unroll
            for (int k = 0; k < 8; ++k) {
                unsigned long long bal = __ballot(mk && (kd == k));
                if (mk && (kd == k)) {
                    int rank = __popcll(bal & below);
                    list[offk[k] + fillk[k] + rank] = (unsigned short)p;
                }
                fillk[k] += __popcll(bal);
            }
        }
        #pragma unroll
        for (int k = 0; k < 8; ++k) {
            int padded = (cnts[k] + 15) & ~15;
            for (int i = cnts[k] + t; i < padded; i += 64) list[offk[k] + i] = 0xFFFFu;
        }
        if (t == 0) {
            int ci = 0;
            #pragma unroll
            for (int k = 0; k < 8; ++k) {
                int nk = (cnts[k] + 15) >> 4;
                for (int j = 0; j < nk; ++j) {
                    chunk_kind[ci] = (short)k;
                    chunk_base[ci] = (short)(offk[k] + j * 16);
                    ++ci;
                }
            }
            nchT_s = ci;
        }
    } else if (t < 96) {
        int i = t - 64, r = i >> 3, k = i & 7, c = 0;
        for (int s = 0; s < 64; ++s) c += (msk[r * 64 + s] && knd[r * 64 + s] == k) ? 1 : 0;
        cntf[(w * ROWS + r) * 8 + k] = (float)c;
    } else if (t < 100) {
        int r = t - 96, c = 0;
        for (int s = 0; s < 64; ++s) c += msk[r * 64 + s];
        denf[w * ROWS + r] = 1.0f / (float)(c > 0 ? c : 1);
    } else if (t >= 128) {
        for (int i = t - 128; i < 32 * 257; i += 384) pool_s[i] = 0.0f;
    }
    __syncthreads();

    const int nchT = nchT_s;

    // -------- barrier-free main loop: each wave owns chunks wv, wv+8, ... -----
    for (int ci = wv; ci < nchT; ci += 8) {
        const int k = (int)chunk_kind[ci];
        const int cb = (int)chunk_base[ci];

        // FF: 16 slots x 64 cols (48 features + 16 zero-pad) into wave slice
        #pragma unroll
        for (int half = 0; half < 2; ++half) {
            int tt = ln + half * 64;
            int s = tt >> 3, g = tt & 7;
            union { unsigned short u[8]; frag f; } hu, lu;
            if (g < 6) {
                int e = list[cb + s];
                float v = vals[e & (WIN - 1)];
                int iscos = (g >= 3);
                int j0 = (iscos ? (g - 3) : g) * 8;
                #pragma unroll
                for (int b = 0; b < 8; ++b) {
                    float rev = __builtin_amdgcn_fractf(v * Bs[j0 + b]);
                    float sv = iscos ? __builtin_amdgcn_cosf(rev)
                                     : __builtin_amdgcn_sinf(rev);
                    split_bf(sv, hu.u[b], lu.u[b]);
                }
            } else {
                #pragma unroll
                for (int b = 0; b < 8; ++b) { hu.u[b] = 0; lu.u[b] = 0; }
            }
            int ao = s * 64 + ((g ^ (s & 7)) << 3);
            *(frag*)&Asl[wv][0][ao] = hu.f;
            *(frag*)&Asl[wv][1][ao] = lu.f;
        }
        // A fragments (within-wave lgkmcnt ordering; no barrier needed)
        frag ah[2], al[2];
        #pragma unroll
        for (int kst = 0; kst < 2; ++kst) {
            int gi = kst * 4 + kq;
            int ao = lr16 * 64 + ((gi ^ (lr16 & 7)) << 3);
            ah[kst] = *(const frag*)&Asl[wv][0][ao];
            al[kst] = *(const frag*)&Asl[wv][1][ao];
        }
        // GEMM1 + gelu + pool atomics, 4 nt-tiles at a time
        for (int ntg = 0; ntg < 4; ++ntg) {
            f32x4 acc[4];
            #pragma unroll
            for (int q = 0; q < 4; ++q) acc[q] = (f32x4)0.0f;
            #pragma unroll
            for (int q = 0; q < 4; ++q) {
                int nt = ntg * 4 + q;
                size_t bo0 = (((size_t)k * 2 + 0) * 16 + nt) * 512 + ln * 8;
                size_t bo1 = (((size_t)k * 2 + 1) * 16 + nt) * 512 + ln * 8;
                frag bh0 = *(const frag*)(w1f_hi + bo0);
                frag bl0 = *(const frag*)(w1f_lo + bo0);
                frag bh1 = *(const frag*)(w1f_hi + bo1);
                frag bl1 = *(const frag*)(w1f_lo + bo1);
                acc[q] = __builtin_amdgcn_mfma_f32_16x16x32_bf16(ah[0], bh0, acc[q], 0, 0, 0);
                acc[q] = __builtin_amdgcn_mfma_f32_16x16x32_bf16(al[0], bh0, acc[q], 0, 0, 0);
                acc[q] = __builtin_amdgcn_mfma_f32_16x16x32_bf16(ah[0], bl0, acc[q], 0, 0, 0);
                acc[q] = __builtin_amdgcn_mfma_f32_16x16x32_bf16(ah[1], bh1, acc[q], 0, 0, 0);
                acc[q] = __builtin_amdgcn_mfma_f32_16x16x32_bf16(al[1], bh1, acc[q], 0, 0, 0);
                acc[q] = __builtin_amdgcn_mfma_f32_16x16x32_bf16(ah[1], bl1, acc[q], 0, 0, 0);
            }
            #pragma unroll
            for (int q = 0; q < 4; ++q) {
                int nt = ntg * 4 + q;
                int col = nt * 16 + lr16;
                float b1v = b1[k * 256 + col];
                #pragma unroll
                for (int r = 0; r < 4; ++r) {
                    int s = kq * 4 + r;
                    int e = list[cb + s];
                    if (e != 0xFFFF) {
                        float g = gelu_fast(acc[q][r] + b1v);
                        atomicAdd(&pool_s[((e >> 6) * 8 + k) * 257 + col], g);
                    }
                }
            }
        }
    }
    __syncthreads();

    // pool write-out: poolf[k][global_row][col] fp32
    for (int i = t; i < 32 * 256; i += 512) {
        int rk = i >> 8, c = i & 255;
        int r = rk >> 3, k = rk & 7;
        poolf[((size_t)k * 4096 + w * ROWS + r) * 256 + c] = pool_s[rk * 257 + c];
    }
}

// ---------------- fuse kernel: GEMM2 + fuse MLP, M=16 rows/block ----------------
__global__ __launch_bounds__(512) void fuse_kernel(
    const short* __restrict__ ws, const float* __restrict__ poolf,
    const float* __restrict__ cntf, const float* __restrict__ denf,
    const int* __restrict__ pt, const int* __restrict__ lid,
    const float* __restrict__ meta, const float* __restrict__ type_emb,
    const float* __restrict__ layer_emb, const float* __restrict__ b2,
    const float* __restrict__ kind_emb, const float* __restrict__ fb1,
    const float* __restrict__ fb2, const float* __restrict__ meta_w,
    const float* __restrict__ meta_b, float* __restrict__ out)
{
    __shared__ __align__(16) short Af[2][2][4096];  // [buf][plane][lane*64+gran*8] 32 KB
    __shared__ __align__(16) float hz[4096];        // [16][256] granule-XOR swizzled
    __shared__ float cnt_s[128], den_s[16], meta_s[64];
    __shared__ int pt_s[16], lid_s[16];

    const short* w2f_hi  = ws + W2F_HI;
    const short* w2f_lo  = ws + W2F_LO;
    const short* fw1f_hi = ws + FW1F_HI;
    const short* fw1f_lo = ws + FW1F_LO;
    const short* fw2f_hi = ws + FW2F_HI;
    const short* fw2f_lo = ws + FW2F_LO;

    const int t = threadIdx.x, blk = blockIdx.x, rb = blk * 16;
    const int wv = t >> 6, ln = t & 63, lr16 = ln & 15, kq = ln >> 4;

    if (t < 16) { pt_s[t] = pt[rb + t]; lid_s[t] = lid[rb + t]; den_s[t] = denf[rb + t]; }
    else if (t < 144) cnt_s[t - 16] = cntf[rb * 8 + (t - 16)];
    else if (t < 208) meta_s[t - 144] = meta[rb * 4 + (t - 144)];

    // staging geometry: thread -> (row sr, 8-col granule sg)
    const int sr = t >> 5, sg = t & 31;
    const int skst = sg >> 2, skq = sg & 3;
    const int slane = skq * 16 + sr;
    const int sdst = slane * 64 + ((skst ^ (sr & 7)) << 3);

    auto stage = [&](int k, int buf) {
        const float* src = poolf + ((size_t)k * 4096 + rb + sr) * 256 + sg * 8;
        f32x4 u0 = *(const f32x4*)src;
        f32x4 u1 = *(const f32x4*)(src + 4);
        union { unsigned short u[8]; frag f; } hu, lu;
        #pragma unroll
        for (int b = 0; b < 4; ++b) {
            split_bf(u0[b], hu.u[b], lu.u[b]);
            split_bf(u1[b], hu.u[b + 4], lu.u[b + 4]);
        }
        *(frag*)&Af[buf][0][sdst] = hu.f;
        *(frag*)&Af[buf][1][sdst] = lu.f;
    };

    stage(0, 0);
    __syncthreads();

    // ---- phase A: h_pre = sum_k pool[k] @ w2[k] ----
    f32x4 acc[2];
    acc[0] = (f32x4)0.0f; acc[1] = (f32x4)0.0f;

    for (int k = 0; k < 8; ++k) {
        const int buf = k & 1;
        if (k < 7) stage(k + 1, buf ^ 1);
        #pragma unroll 2
        for (int kst = 0; kst < 8; ++kst) {
            int ao = ln * 64 + ((kst ^ (ln & 7)) << 3);
            frag ah = *(const frag*)&Af[buf][0][ao];
            frag al = *(const frag*)&Af[buf][1][ao];
            #pragma unroll
            for (int n = 0; n < 2; ++n) {
                size_t bo = (((size_t)k * 8 + kst) * 16 + (wv * 2 + n)) * 512 + ln * 8;
                frag bh = *(const frag*)(w2f_hi + bo);
                frag bl = *(const frag*)(w2f_lo + bo);
                acc[n] = __builtin_amdgcn_mfma_f32_16x16x32_bf16(ah, bh, acc[n], 0, 0, 0);
                acc[n] = __builtin_amdgcn_mfma_f32_16x16x32_bf16(al, bh, acc[n], 0, 0, 0);
                acc[n] = __builtin_amdgcn_mfma_f32_16x16x32_bf16(ah, bl, acc[n], 0, 0, 0);
            }
        }
        __syncthreads();
    }

    // ---- epilogue A: + cnt*(b2+kind_emb), * den -> hz (swizzled) ----
    #pragma unroll
    for (int n = 0; n < 2; ++n) {
        int col = (wv * 2 + n) * 16 + lr16;
        float bks[8];
        #pragma unroll
        for (int k = 0; k < 8; ++k) bks[k] = b2[k * 256 + col] + kind_emb[k * 256 + col];
        #pragma unroll
        for (int r = 0; r < 4; ++r) {
            int row = kq * 4 + r;
            float hv = acc[n][r];
            #pragma unroll
            for (int k = 0; k < 8; ++k) hv = fmaf(cnt_s[row * 8 + k], bks[k], hv);
            hv *= den_s[row];
            hz[row * 256 + ((((col >> 2) ^ (row & 7)) << 2) | (col & 3))] = hv;
        }
    }
    __syncthreads();

    // ---- phase B: z_pre = [h | type_emb | layer_emb] @ fw1 (K=768) ----
    f32x4 az[2];
    az[0] = (f32x4)0.0f; az[1] = (f32x4)0.0f;

    for (int kst = 0; kst < 24; ++kst) {
        const int row = lr16;
        union { unsigned short u[8]; frag f; } hu, lu;
        if (kst < 8) {
            int c0 = kst * 8 + kq * 2;
            f32x4 u0 = *(const f32x4*)&hz[row * 256 + ((c0 ^ (row & 7)) << 2)];
            f32x4 u1 = *(const f32x4*)&hz[row * 256 + (((c0 + 1) ^ (row & 7)) << 2)];
            #pragma unroll
            for (int b = 0; b < 4; ++b) {
                split_bf(u0[b], hu.u[b], lu.u[b]);
                split_bf(u1[b], hu.u[b + 4], lu.u[b + 4]);
            }
        } else {
            const float* eb = (kst < 16) ? type_emb : layer_emb;
            const int* ids = (kst < 16) ? pt_s : lid_s;
            int ko = (kst & 7) * 32 + kq * 8;
            const float* sp = eb + (size_t)ids[row] * 256 + ko;
            f32x4 u0 = *(const f32x4*)sp;
            f32x4 u1 = *(const f32x4*)(sp + 4);
            #pragma unroll
            for (int b = 0; b < 4; ++b) {
                split_bf(u0[b], hu.u[b], lu.u[b]);
                split_bf(u1[b], hu.u[b + 4], lu.u[b + 4]);
            }
        }
        frag ah = hu.f, al = lu.f;
        #pragma unroll
        for (int n = 0; n < 2; ++n) {
            size_t bo = ((size_t)kst * 16 + (wv * 2 + n)) * 512 + ln * 8;
            frag bh = *(const frag*)(fw1f_hi + bo);
            frag bl = *(const frag*)(fw1f_lo + bo);
            az[n] = __builtin_amdgcn_mfma_f32_16x16x32_bf16(ah, bh, az[n], 0, 0, 0);
            az[n] = __builtin_amdgcn_mfma_f32_16x16x32_bf16(al, bh, az[n], 0, 0, 0);
            az[n] = __builtin_amdgcn_mfma_f32_16x16x32_bf16(ah, bl, az[n], 0, 0, 0);
        }
    }
    __syncthreads();   // all hz reads done

    #pragma unroll
    for (int n = 0; n < 2; ++n) {
        int col = (wv * 2 + n) * 16 + lr16;
        float fb1v = fb1[col];
        #pragma unroll
        for (int r = 0; r < 4; ++r) {
            int row = kq * 4 + r;
            float z = gelu_fast(az[n][r] + fb1v);
            hz[row * 256 + ((((col >> 2) ^ (row & 7)) << 2) | (col & 3))] = z;
        }
    }
    __syncthreads();

    // ---- phase C: out = z @ fw2 + fb2 + meta@meta_w + meta_b ----
    f32x4 ao[2];
    ao[0] = (f32x4)0.0f; ao[1] = (f32x4)0.0f;

    for (int kst = 0; kst < 8; ++kst) {
        const int row = lr16;
        int c0 = kst * 8 + kq * 2;
        f32x4 u0 = *(const f32x4*)&hz[row * 256 + ((c0 ^ (row & 7)) << 2)];
        f32x4 u1 = *(const f32x4*)&hz[row * 256 + (((c0 + 1) ^ (row & 7)) << 2)];
        union { unsigned short u[8]; frag f; } hu, lu;
        #pragma unroll
        for (int b = 0; b < 4; ++b) {
            split_bf(u0[b], hu.u[b], lu.u[b]);
            split_bf(u1[b], hu.u[b + 4], lu.u[b + 4]);
        }
        frag ah = hu.f, al = lu.f;
        #pragma unroll
        for (int n = 0; n < 2; ++n) {
            size_t bo = ((size_t)kst * 16 + (wv * 2 + n)) * 512 + ln * 8;
            frag bh = *(const frag*)(fw2f_hi + bo);
            frag bl = *(const frag*)(fw2f_lo + bo);
            ao[n] = __builtin_amdgcn_mfma_f32_16x16x32_bf16(ah, bh, ao[n], 0, 0, 0);
            ao[n] = __builtin_amdgcn_mfma_f32_16x16x32_bf16(al, bh, ao[n], 0, 0, 0);
            ao[n] = __builtin_amdgcn_mfma_f32_16x16x32_bf16(ah, bl, ao[n], 0, 0, 0);
        }
    }

    #pragma unroll
    for (int n = 0; n < 2; ++n) {
        int col = (wv * 2 + n) * 16 + lr16;
        float ob = fb2[col] + meta_b[col];
        float mw0 = meta_w[col], mw1 = meta_w[256 + col];
        float mw2 = meta_w[512 + col], mw3 = meta_w[768 + col];
        #pragma unroll
        for (int r = 0; r < 4; ++r) {
            int row = kq * 4 + r;
            float o = ao[n][r] + ob;
            o = fmaf(meta_s[row * 4 + 0], mw0, o);
            o = fmaf(meta_s[row * 4 + 1], mw1, o);
            o = fmaf(meta_s[row * 4 + 2], mw2, o);
            o = fmaf(meta_s[row * 4 + 3], mw3, o);
            out[(size_t)(rb + row) * 256 + col] = o;
        }
    }
}

extern "C" void kernel_launch(void* const* d_in, const int* in_sizes, int n_in,
                              void* d_out, int out_size, void* d_ws, size_t ws_size,
                              hipStream_t stream) {
    const float* values    = (const float*)d_in[0];
    const int*   kinds     = (const int*)d_in[1];
    const int*   mask      = (const int*)d_in[2];
    const int*   prim_type = (const int*)d_in[3];
    const int*   layer_id  = (const int*)d_in[4];
    const float* meta      = (const float*)d_in[5];
    const float* B_ff      = (const float*)d_in[6];
    const float* kind_emb  = (const float*)d_in[7];
    const float* type_emb  = (const float*)d_in[8];
    const float* layer_emb = (const float*)d_in[9];
    const float* mlp_w1    = (const float*)d_in[10];
    const float* mlp_b1    = (const float*)d_in[11];
    const float* mlp_w2    = (const float*)d_in[12];
    const float* mlp_b2    = (const float*)d_in[13];
    const float* fuse_w1   = (const float*)d_in[14];
    const float* fuse_b1   = (const float*)d_in[15];
    const float* fuse_w2   = (const float*)d_in[16];
    const float* fuse_b2   = (const float*)d_in[17];
    const float* meta_w    = (const float*)d_in[18];
    const float* meta_b    = (const float*)d_in[19];

    short* ws    = (short*)d_ws;
    float* poolf = (float*)((char*)d_ws + POOL_BYTE);
    float* cntf  = (float*)((char*)d_ws + CNT_BYTE);
    float* denf  = (float*)((char*)d_ws + DEN_BYTE);
    float* out   = (float*)d_out;

    prep_kernel<<<224, 512, 0, stream>>>(mlp_w1, mlp_w2, fuse_w1, fuse_w2, ws);
    window_kernel<<<NWIN, 512, 0, stream>>>(values, kinds, mask, B_ff, mlp_b1,
                                            ws, poolf, cntf, denf);
    fuse_kernel<<<256, 512, 0, stream>>>(ws, poolf, cntf, denf, prim_type, layer_id,
                                         meta, type_emb, layer_emb, mlp_b2, kind_emb,
                                         fuse_b1, fuse_b2, meta_w, meta_b, out);
}